// Round 3
// baseline (581.799 us; speedup 1.0000x reference)
//
#include <hip/hip_runtime.h>
#include <hip/hip_bf16.h>
#include <stdint.h>
#include <stddef.h>

typedef __bf16 bf16_t;
typedef __attribute__((ext_vector_type(8))) __bf16 bf16x8;
typedef __attribute__((ext_vector_type(4))) float f32x4;

#define D_MODEL 4096
#define SEQ 1024
#define NH 32
#define HD 128
#define MTOT 2048 /* B*S */

__device__ __forceinline__ void gload_lds16(const void* g, void* l) {
  __builtin_amdgcn_global_load_lds((const __attribute__((address_space(1))) uint32_t*)g,
                                   (__attribute__((address_space(3))) uint32_t*)l, 16, 0, 0);
}

// Decide input dtype from x's bit patterns. bf16 data: low 16 bits of each
// 32-bit word are a valid ~N(0,1) bf16 (exponent in [100,140] w.h.p.).
// fp32 data: low 16 bits are mantissa bits (~uniform) -> ~16% in band.
__global__ void dtype_probe(const uint32_t* __restrict__ x, uint32_t* __restrict__ flag) {
  const int lane = threadIdx.x & 63;
  const uint32_t w = x[lane];
  const uint32_t e = (w >> 7) & 0xFF;
  const bool inband = (e >= 100 && e <= 140);
  const unsigned long long m = __ballot(inband);
  if (lane == 0) *flag = (__popcll(m) >= 32) ? 1u : 0u;  // 1 = bf16, 0 = fp32
}

// Copy/convert n elements of src (dtype per *flag) into bf16 dst. n % 8 == 0.
__global__ __launch_bounds__(256) void conv_bf16(const void* __restrict__ src,
                                                 bf16_t* __restrict__ dst, int n,
                                                 const uint32_t* __restrict__ flag) {
  const int i = (blockIdx.x * 256 + threadIdx.x) * 8;
  if (i >= n) return;
  if (*flag) {
    *(bf16x8*)(dst + i) = *(const bf16x8*)((const bf16_t*)src + i);
  } else {
    const float4 a = *(const float4*)((const float*)src + i);
    const float4 b = *(const float4*)((const float*)src + i + 4);
    bf16x8 v;
    v[0] = (bf16_t)a.x; v[1] = (bf16_t)a.y; v[2] = (bf16_t)a.z; v[3] = (bf16_t)a.w;
    v[4] = (bf16_t)b.x; v[5] = (bf16_t)b.y; v[6] = (bf16_t)b.z; v[7] = (bf16_t)b.w;
    *(bf16x8*)(dst + i) = v;
  }
}

// C[M,N] = A[M,K] * B[N,K]^T   (NT GEMM, m97 structure: 128x128 tile, BK=32)
// MODE 0: write (B,H,S,hd)    (Q and K, RoPE applied later)
// MODE 1: write (B,H,hd,S)    (V, pre-transposed for attention)
// MODE 2: write row-major MxN to d_out, dtype per *flag
template <int MODE>
__global__ __launch_bounds__(256) void gemm_bt(
    const bf16_t* __restrict__ A, const bf16_t* __restrict__ B,
    void* __restrict__ dstv, const uint32_t* __restrict__ flagp) {
  __shared__ __align__(16) bf16_t As[128][32];
  __shared__ __align__(16) bf16_t Bs[128][32];
  const int tid = threadIdx.x;
  const int lane = tid & 63, wid = tid >> 6;
  const int fr = lane & 15, fq = lane >> 4;
  const int wr = wid >> 1, wc = wid & 1;
  const int bm0 = blockIdx.x * 128, bn0 = blockIdx.y * 128;
  const bool isbf = (MODE == 2) ? (*flagp != 0) : true;

  f32x4 acc[4][4];
#pragma unroll
  for (int m = 0; m < 4; m++)
#pragma unroll
    for (int n = 0; n < 4; n++) acc[m][n] = f32x4{0.f, 0.f, 0.f, 0.f};

  for (int k0 = 0; k0 < D_MODEL; k0 += 32) {
#pragma unroll
    for (int is = 0; is < 2; ++is) {
      const int o = (wid << 10) + (is << 12) + (lane << 4);
      const int row = o >> 6, colb = o & 63;
      gload_lds16(A + (size_t)(bm0 + row) * D_MODEL + k0 + (colb >> 1),
                  (char*)(&As[0][0]) + (wid << 10) + (is << 12));
      gload_lds16(B + (size_t)(bn0 + row) * D_MODEL + k0 + (colb >> 1),
                  (char*)(&Bs[0][0]) + (wid << 10) + (is << 12));
    }
    __syncthreads();
    bf16x8 af[4], bfv[4];
#pragma unroll
    for (int i = 0; i < 4; i++) {
      af[i] = *(const bf16x8*)&As[wr * 64 + i * 16 + fr][fq * 8];
      bfv[i] = *(const bf16x8*)&Bs[wc * 64 + i * 16 + fr][fq * 8];
    }
#pragma unroll
    for (int m = 0; m < 4; m++)
#pragma unroll
      for (int n = 0; n < 4; n++)
        acc[m][n] = __builtin_amdgcn_mfma_f32_16x16x32_bf16(af[m], bfv[n], acc[m][n], 0, 0, 0);
    __syncthreads();
  }

#pragma unroll
  for (int m = 0; m < 4; m++) {
#pragma unroll
    for (int n = 0; n < 4; n++) {
      const int gn = bn0 + wc * 64 + n * 16 + fr;
#pragma unroll
      for (int r = 0; r < 4; r++) {
        const int gm = bm0 + wr * 64 + m * 16 + fq * 4 + r;
        const float vv = acc[m][n][r];
        if constexpr (MODE == 0) {
          const int b = gm >> 10, s = gm & (SEQ - 1), h = gn >> 7, dd = gn & (HD - 1);
          ((bf16_t*)dstv)[((size_t)(b * NH + h) * SEQ + s) * HD + dd] = (bf16_t)vv;
        } else if constexpr (MODE == 1) {
          const int b = gm >> 10, s = gm & (SEQ - 1), h = gn >> 7, dd = gn & (HD - 1);
          ((bf16_t*)dstv)[((size_t)(b * NH + h) * HD + dd) * SEQ + s] = (bf16_t)vv;
        } else {
          if (isbf) ((bf16_t*)dstv)[(size_t)gm * D_MODEL + gn] = (bf16_t)vv;
          else      ((float*)dstv)[(size_t)gm * D_MODEL + gn] = vv;
        }
      }
    }
  }
}

// In-place RoPE on q_ws and k_ws, layout (B,H,S,hd). One thread per (r,i) pair.
__global__ __launch_bounds__(256) void rope_kernel(
    bf16_t* __restrict__ q, bf16_t* __restrict__ k,
    const bf16_t* __restrict__ fcos, const bf16_t* __restrict__ fsin) {
  const int PT = MTOT * (D_MODEL / 2);
  const int p = blockIdx.x * blockDim.x + threadIdx.x;
  bf16_t* buf = (p < PT) ? q : k;
  const int pp = p & (PT - 1);
  const int s = (pp >> 6) & (SEQ - 1);
  const int i = pp & 63;
  const float c = (float)fcos[s * 64 + i];
  const float si = (float)fsin[s * 64 + i];
  const float x0 = (float)buf[2 * (size_t)pp];
  const float x1 = (float)buf[2 * (size_t)pp + 1];
  buf[2 * (size_t)pp] = (bf16_t)(x0 * c - x1 * si);
  buf[2 * (size_t)pp + 1] = (bf16_t)(x0 * si + x1 * c);
}

// Flash attention, causal. Grid: (S/64, B*H). 4 waves, each owns 16 q-rows.
// Q,K layout (B,H,S,hd); V layout (B,H,hd,S).
__global__ __launch_bounds__(256) void attn_fwd(
    const bf16_t* __restrict__ Q, const bf16_t* __restrict__ K,
    const bf16_t* __restrict__ V, bf16_t* __restrict__ Out) {
  constexpr float SC = 0.088388347648318447f;  // 1/sqrt(128)
  constexpr float MNEG = -10000.0f;
  __shared__ __align__(16) bf16_t Kt[32][136];
  __shared__ __align__(16) bf16_t Vt[128][40];
  __shared__ __align__(16) bf16_t Pb[4][16][40];
  const int tid = threadIdx.x, lane = tid & 63, wid = tid >> 6;
  const int fr = lane & 15, fq = lane >> 4;
  const int bx = blockIdx.x, bh = blockIdx.y;
  const int q0 = bx * 64 + wid * 16;

  bf16x8 qa[4];
  {
    const bf16_t* qp = Q + ((size_t)bh * SEQ + q0 + fr) * HD + fq * 8;
#pragma unroll
    for (int ks = 0; ks < 4; ++ks) qa[ks] = *(const bf16x8*)(qp + ks * 32);
  }
  f32x4 Oacc[8];
#pragma unroll
  for (int i = 0; i < 8; i++) Oacc[i] = f32x4{0.f, 0.f, 0.f, 0.f};
  float mrow[4] = {MNEG, MNEG, MNEG, MNEG};
  float lrow[4] = {0.f, 0.f, 0.f, 0.f};

  const int nt = 2 * bx + 2;
  for (int t = 0; t < nt; ++t) {
    const int kv0 = t * 32;
#pragma unroll
    for (int pass = 0; pass < 2; ++pass) {
      const int c = pass * 256 + tid;
      {
        const int row = c >> 4, cc = c & 15;
        bf16x8 v = *(const bf16x8*)(K + ((size_t)bh * SEQ + kv0 + row) * HD + cc * 8);
        *(bf16x8*)&Kt[row][cc * 8] = v;
      }
      {
        const int vr = c >> 2, vc = c & 3;
        bf16x8 w = *(const bf16x8*)(V + ((size_t)bh * HD + vr) * SEQ + kv0 + vc * 8);
        *(bf16x8*)&Vt[vr][vc * 8] = w;
      }
    }
    __syncthreads();

    f32x4 sacc[2];
    sacc[0] = f32x4{0.f, 0.f, 0.f, 0.f};
    sacc[1] = f32x4{0.f, 0.f, 0.f, 0.f};
#pragma unroll
    for (int nb = 0; nb < 2; ++nb) {
      const int kvc = nb * 16 + fr;
#pragma unroll
      for (int ks = 0; ks < 4; ++ks) {
        bf16x8 kb = *(const bf16x8*)&Kt[kvc][(ks * 4 + fq) * 8];
        sacc[nb] = __builtin_amdgcn_mfma_f32_16x16x32_bf16(qa[ks], kb, sacc[nb], 0, 0, 0);
      }
    }

    float xv[2][4], al[4];
#pragma unroll
    for (int r = 0; r < 4; ++r) {
      const int qrow = q0 + fq * 4 + r;
#pragma unroll
      for (int nb = 0; nb < 2; ++nb) {
        const int kvp = kv0 + nb * 16 + fr;
        xv[nb][r] = (kvp <= qrow) ? sacc[nb][r] * SC : MNEG;
      }
      float pm = fmaxf(xv[0][r], xv[1][r]);
      pm = fmaxf(pm, __shfl_xor(pm, 1));
      pm = fmaxf(pm, __shfl_xor(pm, 2));
      pm = fmaxf(pm, __shfl_xor(pm, 4));
      pm = fmaxf(pm, __shfl_xor(pm, 8));
      const float mn = fmaxf(mrow[r], pm);
      al[r] = __expf(mrow[r] - mn);
      mrow[r] = mn;
      float ps = 0.f;
#pragma unroll
      for (int nb = 0; nb < 2; ++nb) {
        const float pv = __expf(xv[nb][r] - mn);
        xv[nb][r] = pv;
        ps += pv;
      }
      ps += __shfl_xor(ps, 1);
      ps += __shfl_xor(ps, 2);
      ps += __shfl_xor(ps, 4);
      ps += __shfl_xor(ps, 8);
      lrow[r] = lrow[r] * al[r] + ps;
    }
#pragma unroll
    for (int db = 0; db < 8; ++db)
#pragma unroll
      for (int r = 0; r < 4; ++r) Oacc[db][r] *= al[r];

#pragma unroll
    for (int nb = 0; nb < 2; ++nb)
#pragma unroll
      for (int r = 0; r < 4; ++r)
        Pb[wid][fq * 4 + r][nb * 16 + fr] = (bf16_t)xv[nb][r];
    bf16x8 pa = *(const bf16x8*)&Pb[wid][fr][fq * 8];

#pragma unroll
    for (int db = 0; db < 8; ++db) {
      const int d = db * 16 + fr;
      bf16x8 vb = *(const bf16x8*)&Vt[d][fq * 8];
      Oacc[db] = __builtin_amdgcn_mfma_f32_16x16x32_bf16(pa, vb, Oacc[db], 0, 0, 0);
    }
    __syncthreads();
  }

  const int b = bh >> 5, h = bh & 31;
#pragma unroll
  for (int db = 0; db < 8; ++db) {
    const int d = db * 16 + fr;
#pragma unroll
    for (int r = 0; r < 4; ++r) {
      const int q = q0 + fq * 4 + r;
      const float inv = 1.0f / fmaxf(lrow[r], 1e-20f);
      Out[((size_t)(b * SEQ + q)) * D_MODEL + h * HD + d] = (bf16_t)(Oacc[db][r] * inv);
    }
  }
}

extern "C" void kernel_launch(void* const* d_in, const int* in_sizes, int n_in,
                              void* d_out, int out_size, void* d_ws, size_t ws_size,
                              hipStream_t stream) {
  (void)in_sizes; (void)n_in; (void)out_size;
  const void* x_raw    = d_in[0];
  const void* fcos_raw = d_in[2];
  const void* fsin_raw = d_in[3];
  const void* wq_raw   = d_in[7];
  const void* wk_raw   = d_in[8];
  const void* wv_raw   = d_in[9];
  const void* wo_raw   = d_in[10];

  const size_t NX = (size_t)MTOT * D_MODEL;  // 8,388,608
  const size_t NW = (size_t)D_MODEL * D_MODEL;  // 16,777,216
  const size_t NF = SEQ * (HD / 2);  // 65,536

  // Workspace layout: 1 MB header (flag, fcos, fsin) + bf16 slots.
  char* base = (char*)d_ws;
  uint32_t* flag = (uint32_t*)base;
  bf16_t* fc = (bf16_t*)(base + 4096);
  bf16_t* fs = (bf16_t*)(base + 4096 + 131072);
  bf16_t* elems = (bf16_t*)(base + (1 << 20));
  bf16_t* xc = elems;                 // NX
  bf16_t* w0 = xc + NX;               // NW
  bf16_t* w1 = w0 + NW;               // NW
  bf16_t* q_ws = w1 + NW;             // NX
  bf16_t* k_ws = q_ws + NX;           // NX
  bf16_t* v_ws = k_ws + NX;           // NX
  bf16_t* a_ws = v_ws + NX;           // NX
  const size_t NEED = (1 << 20) + 2 * (5 * NX + 2 * NW);
  if (ws_size < NEED) return;  // diagnostic: finite absmax 7.59 => ws too small

  dtype_probe<<<1, 64, 0, stream>>>((const uint32_t*)x_raw, flag);

  const int cb_x = (int)(NX / (256 * 8));
  const int cb_w = (int)(NW / (256 * 8));
  const int cb_f = (int)(NF / (256 * 8));
  conv_bf16<<<cb_x, 256, 0, stream>>>(x_raw, xc, (int)NX, flag);
  conv_bf16<<<cb_f, 256, 0, stream>>>(fcos_raw, fc, (int)NF, flag);
  conv_bf16<<<cb_f, 256, 0, stream>>>(fsin_raw, fs, (int)NF, flag);

  dim3 gg(MTOT / 128, D_MODEL / 128);
  conv_bf16<<<cb_w, 256, 0, stream>>>(wq_raw, w0, (int)NW, flag);
  gemm_bt<0><<<gg, 256, 0, stream>>>(xc, w0, q_ws, flag);
  conv_bf16<<<cb_w, 256, 0, stream>>>(wk_raw, w1, (int)NW, flag);
  gemm_bt<0><<<gg, 256, 0, stream>>>(xc, w1, k_ws, flag);
  conv_bf16<<<cb_w, 256, 0, stream>>>(wv_raw, w0, (int)NW, flag);
  gemm_bt<1><<<gg, 256, 0, stream>>>(xc, w0, v_ws, flag);

  rope_kernel<<<(2 * MTOT * (D_MODEL / 2)) / 256, 256, 0, stream>>>(q_ws, k_ws, fc, fs);
  attn_fwd<<<dim3(SEQ / 64, 2 * NH), 256, 0, stream>>>(q_ws, k_ws, v_ws, a_ws);

  conv_bf16<<<cb_w, 256, 0, stream>>>(wo_raw, w1, (int)NW, flag);
  gemm_bt<2><<<gg, 256, 0, stream>>>(a_ws, w1, d_out, flag);
}

// Round 4
// 535.840 us; speedup vs baseline: 1.0858x; 1.0858x over previous
//
#include <hip/hip_runtime.h>
#include <hip/hip_bf16.h>
#include <stdint.h>
#include <stddef.h>

typedef __bf16 bf16_t;
typedef __attribute__((ext_vector_type(8))) __bf16 bf16x8;
typedef __attribute__((ext_vector_type(4))) float f32x4;

#define D_MODEL 4096
#define SEQ 1024
#define NH 32
#define HD 128
#define MTOT 2048 /* B*S */

__device__ __forceinline__ void gload_lds16(const void* g, void* l) {
  __builtin_amdgcn_global_load_lds((const __attribute__((address_space(1))) uint32_t*)g,
                                   (__attribute__((address_space(3))) uint32_t*)l, 16, 0, 0);
}

// Decide input dtype from x's bit patterns (kept from round 2 — proven, ~1us).
__global__ void dtype_probe(const uint32_t* __restrict__ x, uint32_t* __restrict__ flag) {
  const int lane = threadIdx.x & 63;
  const uint32_t w = x[lane];
  const uint32_t e = (w >> 7) & 0xFF;
  const bool inband = (e >= 100 && e <= 140);
  const unsigned long long m = __ballot(inband);
  if (lane == 0) *flag = (__popcll(m) >= 32) ? 1u : 0u;  // 1 = bf16, 0 = fp32
}

__global__ __launch_bounds__(256) void conv_bf16(const void* __restrict__ src,
                                                 bf16_t* __restrict__ dst, int n,
                                                 const uint32_t* __restrict__ flag) {
  const int i = (blockIdx.x * 256 + threadIdx.x) * 8;
  if (i >= n) return;
  if (*flag) {
    *(bf16x8*)(dst + i) = *(const bf16x8*)((const bf16_t*)src + i);
  } else {
    const float4 a = *(const float4*)((const float*)src + i);
    const float4 b = *(const float4*)((const float*)src + i + 4);
    bf16x8 v;
    v[0] = (bf16_t)a.x; v[1] = (bf16_t)a.y; v[2] = (bf16_t)a.z; v[3] = (bf16_t)a.w;
    v[4] = (bf16_t)b.x; v[5] = (bf16_t)b.y; v[6] = (bf16_t)b.z; v[7] = (bf16_t)b.w;
    *(bf16x8*)(dst + i) = v;
  }
}

// C[M,N] = A[M,K] * B[N,K]^T   (NT GEMM, m97 structure: 128x128 tile, BK=32)
template <int MODE>
__global__ __launch_bounds__(256) void gemm_bt(
    const bf16_t* __restrict__ A, const bf16_t* __restrict__ B,
    void* __restrict__ dstv, const uint32_t* __restrict__ flagp) {
  __shared__ __align__(16) bf16_t As[128][32];
  __shared__ __align__(16) bf16_t Bs[128][32];
  const int tid = threadIdx.x;
  const int lane = tid & 63, wid = tid >> 6;
  const int fr = lane & 15, fq = lane >> 4;
  const int wr = wid >> 1, wc = wid & 1;
  const int bm0 = blockIdx.x * 128, bn0 = blockIdx.y * 128;
  const bool isbf = (MODE == 2) ? (*flagp != 0) : true;

  f32x4 acc[4][4];
#pragma unroll
  for (int m = 0; m < 4; m++)
#pragma unroll
    for (int n = 0; n < 4; n++) acc[m][n] = f32x4{0.f, 0.f, 0.f, 0.f};

  for (int k0 = 0; k0 < D_MODEL; k0 += 32) {
#pragma unroll
    for (int is = 0; is < 2; ++is) {
      const int o = (wid << 10) + (is << 12) + (lane << 4);
      const int row = o >> 6, colb = o & 63;
      gload_lds16(A + (size_t)(bm0 + row) * D_MODEL + k0 + (colb >> 1),
                  (char*)(&As[0][0]) + (wid << 10) + (is << 12));
      gload_lds16(B + (size_t)(bn0 + row) * D_MODEL + k0 + (colb >> 1),
                  (char*)(&Bs[0][0]) + (wid << 10) + (is << 12));
    }
    __syncthreads();
    bf16x8 af[4], bfv[4];
#pragma unroll
    for (int i = 0; i < 4; i++) {
      af[i] = *(const bf16x8*)&As[wr * 64 + i * 16 + fr][fq * 8];
      bfv[i] = *(const bf16x8*)&Bs[wc * 64 + i * 16 + fr][fq * 8];
    }
#pragma unroll
    for (int m = 0; m < 4; m++)
#pragma unroll
      for (int n = 0; n < 4; n++)
        acc[m][n] = __builtin_amdgcn_mfma_f32_16x16x32_bf16(af[m], bfv[n], acc[m][n], 0, 0, 0);
    __syncthreads();
  }

#pragma unroll
  for (int m = 0; m < 4; m++) {
#pragma unroll
    for (int n = 0; n < 4; n++) {
      const int gn = bn0 + wc * 64 + n * 16 + fr;
#pragma unroll
      for (int r = 0; r < 4; r++) {
        const int gm = bm0 + wr * 64 + m * 16 + fq * 4 + r;
        const float vv = acc[m][n][r];
        if constexpr (MODE == 0) {
          const int b = gm >> 10, s = gm & (SEQ - 1), h = gn >> 7, dd = gn & (HD - 1);
          ((bf16_t*)dstv)[((size_t)(b * NH + h) * SEQ + s) * HD + dd] = (bf16_t)vv;
        } else if constexpr (MODE == 1) {
          const int b = gm >> 10, s = gm & (SEQ - 1), h = gn >> 7, dd = gn & (HD - 1);
          ((bf16_t*)dstv)[((size_t)(b * NH + h) * HD + dd) * SEQ + s] = (bf16_t)vv;
        } else {
          if (isbf) ((bf16_t*)dstv)[(size_t)gm * D_MODEL + gn] = (bf16_t)vv;
          else      ((float*)dstv)[(size_t)gm * D_MODEL + gn] = vv;
        }
      }
    }
  }
}

// In-place RoPE on q_ws and k_ws, layout (B,H,S,hd).
__global__ __launch_bounds__(256) void rope_kernel(
    bf16_t* __restrict__ q, bf16_t* __restrict__ k,
    const bf16_t* __restrict__ fcos, const bf16_t* __restrict__ fsin) {
  const int PT = MTOT * (D_MODEL / 2);
  const int p = blockIdx.x * blockDim.x + threadIdx.x;
  bf16_t* buf = (p < PT) ? q : k;
  const int pp = p & (PT - 1);
  const int s = (pp >> 6) & (SEQ - 1);
  const int i = pp & 63;
  const float c = (float)fcos[s * 64 + i];
  const float si = (float)fsin[s * 64 + i];
  const float x0 = (float)buf[2 * (size_t)pp];
  const float x1 = (float)buf[2 * (size_t)pp + 1];
  buf[2 * (size_t)pp] = (bf16_t)(x0 * c - x1 * si);
  buf[2 * (size_t)pp + 1] = (bf16_t)(x0 * si + x1 * c);
}

// Flash attention v2, causal. Grid: (S/64, B*H), heavy-first (qt = 15-bx).
// 4 waves, each owns 16 q-rows; KVB=64; async reg-staged K/V; deferred lrow reduce.
// Q,K layout (B,H,S,hd); V layout (B,H,hd,S).
__global__ __launch_bounds__(256, 3) void attn_fwd(
    const bf16_t* __restrict__ Q, const bf16_t* __restrict__ K,
    const bf16_t* __restrict__ V, bf16_t* __restrict__ Out) {
  constexpr float SC = 0.088388347648318447f;  // 1/sqrt(128)
  constexpr float MNEG = -10000.0f;
  __shared__ __align__(16) bf16_t Kt[64][136];   // 17408 B, row=272B (s/4 odd: conflict-floor reads)
  __shared__ __align__(16) bf16_t Vt[128][72];   // 18432 B, row=144B
  __shared__ __align__(16) bf16_t Pb[4][16][72]; //  9216 B per-wave P scratch
  const int tid = threadIdx.x, lane = tid & 63, wid = tid >> 6;
  const int fr = lane & 15, fq = lane >> 4;
  const int qt = (int)gridDim.x - 1 - blockIdx.x;  // heavy blocks dispatch first
  const int bh = blockIdx.y;
  const int q0 = qt * 64 + wid * 16;

  const bf16_t* Kbase = K + (size_t)bh * SEQ * HD;
  const bf16_t* Vbase = V + (size_t)bh * HD * SEQ;

  bf16x8 qa[4];
  {
    const bf16_t* qp = Q + ((size_t)bh * SEQ + q0 + fr) * HD + fq * 8;
#pragma unroll
    for (int ks = 0; ks < 4; ++ks) qa[ks] = *(const bf16x8*)(qp + ks * 32);
  }
  f32x4 Oacc[8];
#pragma unroll
  for (int i = 0; i < 8; i++) Oacc[i] = f32x4{0.f, 0.f, 0.f, 0.f};
  float mrow[4] = {MNEG, MNEG, MNEG, MNEG};
  float lrow[4] = {0.f, 0.f, 0.f, 0.f};  // per-lane partial sums (reduced at end)

  bf16x8 kreg[4], vreg[4];
  auto issue = [&](int kv0) {
#pragma unroll
    for (int j = 0; j < 4; ++j) {
      const int idx = j * 256 + tid;
      kreg[j] = *(const bf16x8*)(Kbase + (size_t)(kv0 + (idx >> 4)) * HD + (idx & 15) * 8);
      vreg[j] = *(const bf16x8*)(Vbase + (size_t)(idx >> 3) * SEQ + kv0 + (idx & 7) * 8);
    }
  };
  auto commit = [&]() {
#pragma unroll
    for (int j = 0; j < 4; ++j) {
      const int idx = j * 256 + tid;
      *(bf16x8*)&Kt[idx >> 4][(idx & 15) * 8] = kreg[j];
      *(bf16x8*)&Vt[idx >> 3][(idx & 7) * 8] = vreg[j];
    }
  };

  const int nt = qt + 1;
  issue(0);
  commit();
  __syncthreads();

  for (int t = 0; t < nt; ++t) {
    const bool last = (t == nt - 1);
    if (!last) issue((t + 1) * 64);  // async: latency hides under QK+softmax+PV

    // ---- S = Q K^T (16x64 per wave) ----
    f32x4 sacc[4];
#pragma unroll
    for (int nb = 0; nb < 4; ++nb) sacc[nb] = f32x4{0.f, 0.f, 0.f, 0.f};
    __builtin_amdgcn_s_setprio(1);
#pragma unroll
    for (int nb = 0; nb < 4; ++nb) {
      const int kvc = nb * 16 + fr;
#pragma unroll
      for (int ks = 0; ks < 4; ++ks) {
        bf16x8 kb = *(const bf16x8*)&Kt[kvc][(ks * 4 + fq) * 8];
        sacc[nb] = __builtin_amdgcn_mfma_f32_16x16x32_bf16(qa[ks], kb, sacc[nb], 0, 0, 0);
      }
    }
    __builtin_amdgcn_s_setprio(0);

    // ---- online softmax (mask only on diagonal tile) ----
    float xv[4][4], al[4];
#pragma unroll
    for (int r = 0; r < 4; ++r) {
      const int qrow = q0 + fq * 4 + r;
#pragma unroll
      for (int nb = 0; nb < 4; ++nb) {
        const float xx = sacc[nb][r] * SC;
        xv[nb][r] = (!last || (t * 64 + nb * 16 + fr) <= qrow) ? xx : MNEG;
      }
      float pm = fmaxf(fmaxf(xv[0][r], xv[1][r]), fmaxf(xv[2][r], xv[3][r]));
      pm = fmaxf(pm, __shfl_xor(pm, 1));
      pm = fmaxf(pm, __shfl_xor(pm, 2));
      pm = fmaxf(pm, __shfl_xor(pm, 4));
      pm = fmaxf(pm, __shfl_xor(pm, 8));
      const float mn = fmaxf(mrow[r], pm);
      al[r] = __expf(mrow[r] - mn);
      mrow[r] = mn;
      float ps = 0.f;
#pragma unroll
      for (int nb = 0; nb < 4; ++nb) {
        const float pv = __expf(xv[nb][r] - mn);
        xv[nb][r] = pv;
        ps += pv;
      }
      lrow[r] = lrow[r] * al[r] + ps;  // per-lane partial, no shfl here
    }
#pragma unroll
    for (int db = 0; db < 8; ++db)
#pragma unroll
      for (int r = 0; r < 4; ++r) Oacc[db][r] *= al[r];

    // ---- P (C-layout) -> per-wave LDS -> two A-frags (kv 0-31, 32-63) ----
#pragma unroll
    for (int nb = 0; nb < 4; ++nb)
#pragma unroll
      for (int r = 0; r < 4; ++r)
        Pb[wid][fq * 4 + r][nb * 16 + fr] = (bf16_t)xv[nb][r];
    bf16x8 pa0 = *(const bf16x8*)&Pb[wid][fr][fq * 8];
    bf16x8 pa1 = *(const bf16x8*)&Pb[wid][fr][32 + fq * 8];

    // ---- O += P V ----
    __builtin_amdgcn_s_setprio(1);
#pragma unroll
    for (int db = 0; db < 8; ++db) {
      const int d = db * 16 + fr;
      bf16x8 vb0 = *(const bf16x8*)&Vt[d][fq * 8];
      bf16x8 vb1 = *(const bf16x8*)&Vt[d][32 + fq * 8];
      Oacc[db] = __builtin_amdgcn_mfma_f32_16x16x32_bf16(pa0, vb0, Oacc[db], 0, 0, 0);
      Oacc[db] = __builtin_amdgcn_mfma_f32_16x16x32_bf16(pa1, vb1, Oacc[db], 0, 0, 0);
    }
    __builtin_amdgcn_s_setprio(0);

    if (!last) {
      __syncthreads();   // all waves done reading Kt/Vt
      commit();          // staged regs -> LDS (compiler waits vmcnt at use)
      __syncthreads();   // tile t+1 visible
    }
  }

  float linv[4];
#pragma unroll
  for (int r = 0; r < 4; ++r) {
    float ps = lrow[r];
    ps += __shfl_xor(ps, 1);
    ps += __shfl_xor(ps, 2);
    ps += __shfl_xor(ps, 4);
    ps += __shfl_xor(ps, 8);
    linv[r] = 1.0f / fmaxf(ps, 1e-20f);
  }

  const int b = bh >> 5, h = bh & 31;
#pragma unroll
  for (int db = 0; db < 8; ++db) {
    const int d = db * 16 + fr;
#pragma unroll
    for (int r = 0; r < 4; ++r) {
      const int q = q0 + fq * 4 + r;
      Out[((size_t)(b * SEQ + q)) * D_MODEL + h * HD + d] = (bf16_t)(Oacc[db][r] * linv[r]);
    }
  }
}

extern "C" void kernel_launch(void* const* d_in, const int* in_sizes, int n_in,
                              void* d_out, int out_size, void* d_ws, size_t ws_size,
                              hipStream_t stream) {
  (void)in_sizes; (void)n_in; (void)out_size;
  const void* x_raw    = d_in[0];
  const void* fcos_raw = d_in[2];
  const void* fsin_raw = d_in[3];
  const void* wq_raw   = d_in[7];
  const void* wk_raw   = d_in[8];
  const void* wv_raw   = d_in[9];
  const void* wo_raw   = d_in[10];

  const size_t NX = (size_t)MTOT * D_MODEL;
  const size_t NW = (size_t)D_MODEL * D_MODEL;
  const size_t NF = SEQ * (HD / 2);

  char* base = (char*)d_ws;
  uint32_t* flag = (uint32_t*)base;
  bf16_t* fc = (bf16_t*)(base + 4096);
  bf16_t* fs = (bf16_t*)(base + 4096 + 131072);
  bf16_t* elems = (bf16_t*)(base + (1 << 20));
  bf16_t* xc = elems;
  bf16_t* w0 = xc + NX;
  bf16_t* w1 = w0 + NW;
  bf16_t* q_ws = w1 + NW;
  bf16_t* k_ws = q_ws + NX;
  bf16_t* v_ws = k_ws + NX;
  bf16_t* a_ws = v_ws + NX;
  const size_t NEED = (1 << 20) + 2 * (5 * NX + 2 * NW);
  if (ws_size < NEED) return;

  dtype_probe<<<1, 64, 0, stream>>>((const uint32_t*)x_raw, flag);

  const int cb_x = (int)(NX / (256 * 8));
  const int cb_w = (int)(NW / (256 * 8));
  const int cb_f = (int)(NF / (256 * 8));
  conv_bf16<<<cb_x, 256, 0, stream>>>(x_raw, xc, (int)NX, flag);
  conv_bf16<<<cb_f, 256, 0, stream>>>(fcos_raw, fc, (int)NF, flag);
  conv_bf16<<<cb_f, 256, 0, stream>>>(fsin_raw, fs, (int)NF, flag);

  dim3 gg(MTOT / 128, D_MODEL / 128);
  conv_bf16<<<cb_w, 256, 0, stream>>>(wq_raw, w0, (int)NW, flag);
  gemm_bt<0><<<gg, 256, 0, stream>>>(xc, w0, q_ws, flag);
  conv_bf16<<<cb_w, 256, 0, stream>>>(wk_raw, w1, (int)NW, flag);
  gemm_bt<0><<<gg, 256, 0, stream>>>(xc, w1, k_ws, flag);
  conv_bf16<<<cb_w, 256, 0, stream>>>(wv_raw, w0, (int)NW, flag);
  gemm_bt<1><<<gg, 256, 0, stream>>>(xc, w0, v_ws, flag);

  rope_kernel<<<(2 * MTOT * (D_MODEL / 2)) / 256, 256, 0, stream>>>(q_ws, k_ws, fc, fs);
  attn_fwd<<<dim3(SEQ / 64, 2 * NH), 256, 0, stream>>>(q_ws, k_ws, v_ws, a_ws);

  conv_bf16<<<cb_w, 256, 0, stream>>>(wo_raw, w1, (int)NW, flag);
  gemm_bt<2><<<gg, 256, 0, stream>>>(a_ws, w1, d_out, flag);
}

// Round 5
// 456.660 us; speedup vs baseline: 1.2740x; 1.1734x over previous
//
#include <hip/hip_runtime.h>
#include <hip/hip_bf16.h>
#include <stdint.h>
#include <stddef.h>

typedef __bf16 bf16_t;
typedef __attribute__((ext_vector_type(8))) __bf16 bf16x8;
typedef __attribute__((ext_vector_type(4))) float f32x4;

#define D_MODEL 4096
#define SEQ 1024
#define NH 32
#define HD 128
#define MTOT 2048 /* B*S */

#define VMCNT(n) asm volatile("s_waitcnt vmcnt(" #n ")" ::: "memory")
#define SCHED0() __builtin_amdgcn_sched_barrier(0)

__device__ __forceinline__ void gload_lds16(const void* g, void* l) {
  __builtin_amdgcn_global_load_lds((const __attribute__((address_space(1))) uint32_t*)g,
                                   (__attribute__((address_space(3))) uint32_t*)l, 16, 0, 0);
}

// Decide input dtype from x's bit patterns (proven round 2).
__global__ void dtype_probe(const uint32_t* __restrict__ x, uint32_t* __restrict__ flag) {
  const int lane = threadIdx.x & 63;
  const uint32_t w = x[lane];
  const uint32_t e = (w >> 7) & 0xFF;
  const bool inband = (e >= 100 && e <= 140);
  const unsigned long long m = __ballot(inband);
  if (lane == 0) *flag = (__popcll(m) >= 32) ? 1u : 0u;  // 1 = bf16, 0 = fp32
}

__global__ __launch_bounds__(256) void conv_bf16(const void* __restrict__ src,
                                                 bf16_t* __restrict__ dst, int n,
                                                 const uint32_t* __restrict__ flag) {
  const int i = (blockIdx.x * 256 + threadIdx.x) * 8;
  if (i >= n) return;
  if (*flag) {
    *(bf16x8*)(dst + i) = *(const bf16x8*)((const bf16_t*)src + i);
  } else {
    const float4 a = *(const float4*)((const float*)src + i);
    const float4 b = *(const float4*)((const float*)src + i + 4);
    bf16x8 v;
    v[0] = (bf16_t)a.x; v[1] = (bf16_t)a.y; v[2] = (bf16_t)a.z; v[3] = (bf16_t)a.w;
    v[4] = (bf16_t)b.x; v[5] = (bf16_t)b.y; v[6] = (bf16_t)b.z; v[7] = (bf16_t)b.w;
    *(bf16x8*)(dst + i) = v;
  }
}

// C[M,N] = A[M,K] * B[N,K]^T — deep-pipelined NT GEMM.
// BM=128, BN=256, BK=64, 512 thr (8 waves 2Mx4N), 3 LDS buffers, prefetch depth 2,
// counted vmcnt(12) (T4), row-XOR LDS swizzle (T2, both-sides), setprio (T5).
// MODE 0: write (B,H,S,hd);  MODE 1: write (B,H,hd,S);  MODE 2: row-major, dtype per flag.
template <int MODE>
__global__ __launch_bounds__(512, 2) void gemm_bt(
    const bf16_t* __restrict__ A, const bf16_t* __restrict__ B,
    void* __restrict__ dstv, const uint32_t* __restrict__ flagp) {
  // per buffer: A 128x64 bf16 = 16384 B, B 256x64 bf16 = 32768 B -> 49152 B; x3 = 144 KiB
  __shared__ __align__(16) char smem[3 * 49152];
  const int tid = threadIdx.x;
  const int lane = tid & 63, wid = tid >> 6;
  const int fr = lane & 15, fq = lane >> 4;
  const int wm = wid >> 2, wn = wid & 3;
  const int bm0 = blockIdx.x * 128, bn0 = blockIdx.y * 256;
  const bool isbf = (MODE == 2) ? (*flagp != 0) : true;

  // stage K-tile t into buffer bi: linear LDS dest, inverse-swizzled global source
  auto stage = [&](int t, int bi) {
    const int k0 = t * 64;
    char* ab = smem + bi * 49152;
    char* bb = ab + 16384;
#pragma unroll
    for (int j = 0; j < 2; ++j) {
      const int o = j * 8192 + tid * 16;
      const int row = o >> 7, ch = (o >> 4) & 7;
      gload_lds16(A + (size_t)(bm0 + row) * D_MODEL + k0 + ((ch ^ (row & 7)) * 8), ab + o);
    }
#pragma unroll
    for (int j = 0; j < 4; ++j) {
      const int o = j * 8192 + tid * 16;
      const int row = o >> 7, ch = (o >> 4) & 7;
      gload_lds16(B + (size_t)(bn0 + row) * D_MODEL + k0 + ((ch ^ (row & 7)) * 8), bb + o);
    }
  };

  f32x4 acc[4][4];
#pragma unroll
  for (int m = 0; m < 4; m++)
#pragma unroll
    for (int n = 0; n < 4; n++) acc[m][n] = f32x4{0.f, 0.f, 0.f, 0.f};

  auto compute = [&](int bi) {
    const char* ab = smem + bi * 49152;
    const char* bb = ab + 16384;
#pragma unroll
    for (int kk = 0; kk < 2; ++kk) {
      const int swz = ((kk * 4 + fq) ^ (fr & 7)) << 4;  // row&7 == fr&7 (bases are mult of 8)
      bf16x8 af[4], bfv[4];
#pragma unroll
      for (int m = 0; m < 4; ++m)
        af[m] = *(const bf16x8*)(ab + (wm * 64 + m * 16 + fr) * 128 + swz);
#pragma unroll
      for (int n = 0; n < 4; ++n)
        bfv[n] = *(const bf16x8*)(bb + (wn * 64 + n * 16 + fr) * 128 + swz);
      __builtin_amdgcn_s_setprio(1);
#pragma unroll
      for (int m = 0; m < 4; ++m)
#pragma unroll
        for (int n = 0; n < 4; ++n)
          acc[m][n] = __builtin_amdgcn_mfma_f32_16x16x32_bf16(af[m], bfv[n], acc[m][n], 0, 0, 0);
      __builtin_amdgcn_s_setprio(0);
    }
  };

  const int NT = D_MODEL / 64;  // 64
  stage(0, 0);
  stage(1, 1);
  int cur = 0, nxt = 2;
  for (int t = 0; t < NT - 2; ++t) {
    stage(t + 2, nxt);          // readers of buf nxt (tile t-1) retired at last barrier
    VMCNT(12);                  // my tile-t loads landed (12 = 2 tiles x 6 in flight)
    __builtin_amdgcn_s_barrier();  // everyone's tile-t loads landed
    SCHED0();
    compute(cur);
    __builtin_amdgcn_s_barrier();  // all waves done reading buf cur
    SCHED0();
    cur = (cur == 2) ? 0 : cur + 1;
    nxt = (nxt == 2) ? 0 : nxt + 1;
  }
  VMCNT(6);
  __builtin_amdgcn_s_barrier();
  SCHED0();
  compute(cur);
  __builtin_amdgcn_s_barrier();
  SCHED0();
  cur = (cur == 2) ? 0 : cur + 1;
  VMCNT(0);
  __builtin_amdgcn_s_barrier();
  SCHED0();
  compute(cur);

#pragma unroll
  for (int m = 0; m < 4; m++) {
#pragma unroll
    for (int n = 0; n < 4; n++) {
      const int gn = bn0 + wn * 64 + n * 16 + fr;
#pragma unroll
      for (int r = 0; r < 4; r++) {
        const int gm = bm0 + wm * 64 + m * 16 + fq * 4 + r;
        const float vv = acc[m][n][r];
        if constexpr (MODE == 0) {
          const int b = gm >> 10, s = gm & (SEQ - 1), h = gn >> 7, dd = gn & (HD - 1);
          ((bf16_t*)dstv)[((size_t)(b * NH + h) * SEQ + s) * HD + dd] = (bf16_t)vv;
        } else if constexpr (MODE == 1) {
          const int b = gm >> 10, s = gm & (SEQ - 1), h = gn >> 7, dd = gn & (HD - 1);
          ((bf16_t*)dstv)[((size_t)(b * NH + h) * HD + dd) * SEQ + s] = (bf16_t)vv;
        } else {
          if (isbf) ((bf16_t*)dstv)[(size_t)gm * D_MODEL + gn] = (bf16_t)vv;
          else      ((float*)dstv)[(size_t)gm * D_MODEL + gn] = vv;
        }
      }
    }
  }
}

// In-place RoPE on q_ws and k_ws, layout (B,H,S,hd).
__global__ __launch_bounds__(256) void rope_kernel(
    bf16_t* __restrict__ q, bf16_t* __restrict__ k,
    const bf16_t* __restrict__ fcos, const bf16_t* __restrict__ fsin) {
  const int PT = MTOT * (D_MODEL / 2);
  const int p = blockIdx.x * blockDim.x + threadIdx.x;
  bf16_t* buf = (p < PT) ? q : k;
  const int pp = p & (PT - 1);
  const int s = (pp >> 6) & (SEQ - 1);
  const int i = pp & 63;
  const float c = (float)fcos[s * 64 + i];
  const float si = (float)fsin[s * 64 + i];
  const float x0 = (float)buf[2 * (size_t)pp];
  const float x1 = (float)buf[2 * (size_t)pp + 1];
  buf[2 * (size_t)pp] = (bf16_t)(x0 * c - x1 * si);
  buf[2 * (size_t)pp + 1] = (bf16_t)(x0 * si + x1 * c);
}

// Flash attention, causal (round-3 version, unchanged).
__global__ __launch_bounds__(256, 3) void attn_fwd(
    const bf16_t* __restrict__ Q, const bf16_t* __restrict__ K,
    const bf16_t* __restrict__ V, bf16_t* __restrict__ Out) {
  constexpr float SC = 0.088388347648318447f;
  constexpr float MNEG = -10000.0f;
  __shared__ __align__(16) bf16_t Kt[64][136];
  __shared__ __align__(16) bf16_t Vt[128][72];
  __shared__ __align__(16) bf16_t Pb[4][16][72];
  const int tid = threadIdx.x, lane = tid & 63, wid = tid >> 6;
  const int fr = lane & 15, fq = lane >> 4;
  const int qt = (int)gridDim.x - 1 - blockIdx.x;
  const int bh = blockIdx.y;
  const int q0 = qt * 64 + wid * 16;

  const bf16_t* Kbase = K + (size_t)bh * SEQ * HD;
  const bf16_t* Vbase = V + (size_t)bh * HD * SEQ;

  bf16x8 qa[4];
  {
    const bf16_t* qp = Q + ((size_t)bh * SEQ + q0 + fr) * HD + fq * 8;
#pragma unroll
    for (int ks = 0; ks < 4; ++ks) qa[ks] = *(const bf16x8*)(qp + ks * 32);
  }
  f32x4 Oacc[8];
#pragma unroll
  for (int i = 0; i < 8; i++) Oacc[i] = f32x4{0.f, 0.f, 0.f, 0.f};
  float mrow[4] = {MNEG, MNEG, MNEG, MNEG};
  float lrow[4] = {0.f, 0.f, 0.f, 0.f};

  bf16x8 kreg[4], vreg[4];
  auto issue = [&](int kv0) {
#pragma unroll
    for (int j = 0; j < 4; ++j) {
      const int idx = j * 256 + tid;
      kreg[j] = *(const bf16x8*)(Kbase + (size_t)(kv0 + (idx >> 4)) * HD + (idx & 15) * 8);
      vreg[j] = *(const bf16x8*)(Vbase + (size_t)(idx >> 3) * SEQ + kv0 + (idx & 7) * 8);
    }
  };
  auto commit = [&]() {
#pragma unroll
    for (int j = 0; j < 4; ++j) {
      const int idx = j * 256 + tid;
      *(bf16x8*)&Kt[idx >> 4][(idx & 15) * 8] = kreg[j];
      *(bf16x8*)&Vt[idx >> 3][(idx & 7) * 8] = vreg[j];
    }
  };

  const int nt = qt + 1;
  issue(0);
  commit();
  __syncthreads();

  for (int t = 0; t < nt; ++t) {
    const bool last = (t == nt - 1);
    if (!last) issue((t + 1) * 64);

    f32x4 sacc[4];
#pragma unroll
    for (int nb = 0; nb < 4; ++nb) sacc[nb] = f32x4{0.f, 0.f, 0.f, 0.f};
    __builtin_amdgcn_s_setprio(1);
#pragma unroll
    for (int nb = 0; nb < 4; ++nb) {
      const int kvc = nb * 16 + fr;
#pragma unroll
      for (int ks = 0; ks < 4; ++ks) {
        bf16x8 kb = *(const bf16x8*)&Kt[kvc][(ks * 4 + fq) * 8];
        sacc[nb] = __builtin_amdgcn_mfma_f32_16x16x32_bf16(qa[ks], kb, sacc[nb], 0, 0, 0);
      }
    }
    __builtin_amdgcn_s_setprio(0);

    float xv[4][4], al[4];
#pragma unroll
    for (int r = 0; r < 4; ++r) {
      const int qrow = q0 + fq * 4 + r;
#pragma unroll
      for (int nb = 0; nb < 4; ++nb) {
        const float xx = sacc[nb][r] * SC;
        xv[nb][r] = (!last || (t * 64 + nb * 16 + fr) <= qrow) ? xx : MNEG;
      }
      float pm = fmaxf(fmaxf(xv[0][r], xv[1][r]), fmaxf(xv[2][r], xv[3][r]));
      pm = fmaxf(pm, __shfl_xor(pm, 1));
      pm = fmaxf(pm, __shfl_xor(pm, 2));
      pm = fmaxf(pm, __shfl_xor(pm, 4));
      pm = fmaxf(pm, __shfl_xor(pm, 8));
      const float mn = fmaxf(mrow[r], pm);
      al[r] = __expf(mrow[r] - mn);
      mrow[r] = mn;
      float ps = 0.f;
#pragma unroll
      for (int nb = 0; nb < 4; ++nb) {
        const float pv = __expf(xv[nb][r] - mn);
        xv[nb][r] = pv;
        ps += pv;
      }
      lrow[r] = lrow[r] * al[r] + ps;
    }
#pragma unroll
    for (int db = 0; db < 8; ++db)
#pragma unroll
      for (int r = 0; r < 4; ++r) Oacc[db][r] *= al[r];

#pragma unroll
    for (int nb = 0; nb < 4; ++nb)
#pragma unroll
      for (int r = 0; r < 4; ++r)
        Pb[wid][fq * 4 + r][nb * 16 + fr] = (bf16_t)xv[nb][r];
    bf16x8 pa0 = *(const bf16x8*)&Pb[wid][fr][fq * 8];
    bf16x8 pa1 = *(const bf16x8*)&Pb[wid][fr][32 + fq * 8];

    __builtin_amdgcn_s_setprio(1);
#pragma unroll
    for (int db = 0; db < 8; ++db) {
      const int d = db * 16 + fr;
      bf16x8 vb0 = *(const bf16x8*)&Vt[d][fq * 8];
      bf16x8 vb1 = *(const bf16x8*)&Vt[d][32 + fq * 8];
      Oacc[db] = __builtin_amdgcn_mfma_f32_16x16x32_bf16(pa0, vb0, Oacc[db], 0, 0, 0);
      Oacc[db] = __builtin_amdgcn_mfma_f32_16x16x32_bf16(pa1, vb1, Oacc[db], 0, 0, 0);
    }
    __builtin_amdgcn_s_setprio(0);

    if (!last) {
      __syncthreads();
      commit();
      __syncthreads();
    }
  }

  float linv[4];
#pragma unroll
  for (int r = 0; r < 4; ++r) {
    float ps = lrow[r];
    ps += __shfl_xor(ps, 1);
    ps += __shfl_xor(ps, 2);
    ps += __shfl_xor(ps, 4);
    ps += __shfl_xor(ps, 8);
    linv[r] = 1.0f / fmaxf(ps, 1e-20f);
  }

  const int b = bh >> 5, h = bh & 31;
#pragma unroll
  for (int db = 0; db < 8; ++db) {
    const int d = db * 16 + fr;
#pragma unroll
    for (int r = 0; r < 4; ++r) {
      const int q = q0 + fq * 4 + r;
      Out[((size_t)(b * SEQ + q)) * D_MODEL + h * HD + d] = (bf16_t)(Oacc[db][r] * linv[r]);
    }
  }
}

extern "C" void kernel_launch(void* const* d_in, const int* in_sizes, int n_in,
                              void* d_out, int out_size, void* d_ws, size_t ws_size,
                              hipStream_t stream) {
  (void)in_sizes; (void)n_in; (void)out_size;
  const void* x_raw    = d_in[0];
  const void* fcos_raw = d_in[2];
  const void* fsin_raw = d_in[3];
  const void* wq_raw   = d_in[7];
  const void* wk_raw   = d_in[8];
  const void* wv_raw   = d_in[9];
  const void* wo_raw   = d_in[10];

  const size_t NX = (size_t)MTOT * D_MODEL;
  const size_t NW = (size_t)D_MODEL * D_MODEL;
  const size_t NF = SEQ * (HD / 2);

  char* base = (char*)d_ws;
  uint32_t* flag = (uint32_t*)base;
  bf16_t* fc = (bf16_t*)(base + 4096);
  bf16_t* fs = (bf16_t*)(base + 4096 + 131072);
  bf16_t* elems = (bf16_t*)(base + (1 << 20));
  bf16_t* xc = elems;
  bf16_t* w0 = xc + NX;
  bf16_t* w1 = w0 + NW;
  bf16_t* q_ws = w1 + NW;
  bf16_t* k_ws = q_ws + NX;
  bf16_t* v_ws = k_ws + NX;
  bf16_t* a_ws = v_ws + NX;
  const size_t NEED = (1 << 20) + 2 * (5 * NX + 2 * NW);
  if (ws_size < NEED) return;

  dtype_probe<<<1, 64, 0, stream>>>((const uint32_t*)x_raw, flag);

  const int cb_x = (int)(NX / (256 * 8));
  const int cb_w = (int)(NW / (256 * 8));
  const int cb_f = (int)(NF / (256 * 8));
  conv_bf16<<<cb_x, 256, 0, stream>>>(x_raw, xc, (int)NX, flag);
  conv_bf16<<<cb_f, 256, 0, stream>>>(fcos_raw, fc, (int)NF, flag);
  conv_bf16<<<cb_f, 256, 0, stream>>>(fsin_raw, fs, (int)NF, flag);

  dim3 gg(MTOT / 128, D_MODEL / 256);
  conv_bf16<<<cb_w, 256, 0, stream>>>(wq_raw, w0, (int)NW, flag);
  gemm_bt<0><<<gg, 512, 0, stream>>>(xc, w0, q_ws, flag);
  conv_bf16<<<cb_w, 256, 0, stream>>>(wk_raw, w1, (int)NW, flag);
  gemm_bt<0><<<gg, 512, 0, stream>>>(xc, w1, k_ws, flag);
  conv_bf16<<<cb_w, 256, 0, stream>>>(wv_raw, w0, (int)NW, flag);
  gemm_bt<1><<<gg, 512, 0, stream>>>(xc, w0, v_ws, flag);

  rope_kernel<<<(2 * MTOT * (D_MODEL / 2)) / 256, 256, 0, stream>>>(q_ws, k_ws, fc, fs);
  attn_fwd<<<dim3(SEQ / 64, 2 * NH), 256, 0, stream>>>(q_ws, k_ws, v_ws, a_ws);

  conv_bf16<<<cb_w, 256, 0, stream>>>(wo_raw, w1, (int)NW, flag);
  gemm_bt<2><<<gg, 512, 0, stream>>>(a_ws, w1, d_out, flag);
}

// Round 6
// 438.871 us; speedup vs baseline: 1.3257x; 1.0405x over previous
//
#include <hip/hip_runtime.h>
#include <hip/hip_bf16.h>
#include <stdint.h>
#include <stddef.h>

typedef __bf16 bf16_t;
typedef __attribute__((ext_vector_type(8))) __bf16 bf16x8;
typedef __attribute__((ext_vector_type(4))) float f32x4;

#define D_MODEL 4096
#define SEQ 1024
#define NH 32
#define HD 128
#define MTOT 2048 /* B*S */

#define VMCNT(n) asm volatile("s_waitcnt vmcnt(" #n ")" ::: "memory")
#define LGKM0() asm volatile("s_waitcnt lgkmcnt(0)" ::: "memory")
#define SCHED0() __builtin_amdgcn_sched_barrier(0)

__device__ __forceinline__ void gload_lds16(const void* g, void* l) {
  __builtin_amdgcn_global_load_lds((const __attribute__((address_space(1))) uint32_t*)g,
                                   (__attribute__((address_space(3))) uint32_t*)l, 16, 0, 0);
}

// Decide input dtype from x's bit patterns (proven round 2).
__global__ void dtype_probe(const uint32_t* __restrict__ x, uint32_t* __restrict__ flag) {
  const int lane = threadIdx.x & 63;
  const uint32_t w = x[lane];
  const uint32_t e = (w >> 7) & 0xFF;
  const bool inband = (e >= 100 && e <= 140);
  const unsigned long long m = __ballot(inband);
  if (lane == 0) *flag = (__popcll(m) >= 32) ? 1u : 0u;  // 1 = bf16, 0 = fp32
}

__global__ __launch_bounds__(256) void conv_bf16(const void* __restrict__ src,
                                                 bf16_t* __restrict__ dst, int n,
                                                 const uint32_t* __restrict__ flag) {
  const int i = (blockIdx.x * 256 + threadIdx.x) * 8;
  if (i >= n) return;
  if (*flag) {
    *(bf16x8*)(dst + i) = *(const bf16x8*)((const bf16_t*)src + i);
  } else {
    const float4 a = *(const float4*)((const float*)src + i);
    const float4 b = *(const float4*)((const float*)src + i + 4);
    bf16x8 v;
    v[0] = (bf16_t)a.x; v[1] = (bf16_t)a.y; v[2] = (bf16_t)a.z; v[3] = (bf16_t)a.w;
    v[4] = (bf16_t)b.x; v[5] = (bf16_t)b.y; v[6] = (bf16_t)b.z; v[7] = (bf16_t)b.w;
    *(bf16x8*)(dst + i) = v;
  }
}

// C[M,N] = A[M,K] * B[N,K]^T — 8-phase-style deep-pipelined NT GEMM (T2+T3+T4+T5).
// BM=128, BN=256, BK=64, 512 thr (8 waves 2Mx4N), 3 LDS buffers, prefetch depth 2.
// Per K-tile: 2 phases of {8 ds_read || 3 gload_lds -> barrier -> lgkm0 -> 16 MFMA -> barrier},
// counted VMCNT(6) once per K-tile (never 0 in steady state).
template <int MODE>
__global__ __launch_bounds__(512, 2) void gemm_bt(
    const bf16_t* __restrict__ A, const bf16_t* __restrict__ B,
    void* __restrict__ dstv, const uint32_t* __restrict__ flagp) {
  __shared__ __align__(16) char smem[3 * 49152];
  const int tid = threadIdx.x;
  const int lane = tid & 63, wid = tid >> 6;
  const int fr = lane & 15, fq = lane >> 4;
  const int wm = wid >> 2, wn = wid & 3;
  const int bm0 = blockIdx.x * 128, bn0 = blockIdx.y * 256;
  const bool isbf = (MODE == 2) ? (*flagp != 0) : true;

  // half h (0/1) of staging tile t into buffer bi: 1 A-load + 2 B-loads per thread.
  auto stage_half = [&](int t, int bi, int h) {
    const int k0 = t * 64;
    char* ab = smem + bi * 49152;
    char* bb = ab + 16384;
    {
      const int o = h * 8192 + tid * 16;
      const int row = o >> 7, ch = (o >> 4) & 7;
      gload_lds16(A + (size_t)(bm0 + row) * D_MODEL + k0 + ((ch ^ (row & 7)) * 8), ab + o);
    }
#pragma unroll
    for (int j = 0; j < 2; ++j) {
      const int o = (h * 2 + j) * 8192 + tid * 16;
      const int row = o >> 7, ch = (o >> 4) & 7;
      gload_lds16(B + (size_t)(bn0 + row) * D_MODEL + k0 + ((ch ^ (row & 7)) * 8), bb + o);
    }
  };

  f32x4 acc[4][4];
#pragma unroll
  for (int m = 0; m < 4; m++)
#pragma unroll
    for (int n = 0; n < 4; n++) acc[m][n] = f32x4{0.f, 0.f, 0.f, 0.f};

  // one phase: frag ds_reads (buffer bi, sub-K kk) || optional stage half -> bar -> lgkm0 -> 16 MFMA
  auto phase = [&](int bi, int kk, bool do_stage, int ts, int bs, int h) {
    const char* ab = smem + bi * 49152;
    const char* bb = ab + 16384;
    const int swz = ((kk * 4 + fq) ^ (fr & 7)) << 4;  // row&7 == fr&7 (row bases mult of 8)
    bf16x8 af[4], bfv[4];
#pragma unroll
    for (int m = 0; m < 4; ++m)
      af[m] = *(const bf16x8*)(ab + (wm * 64 + m * 16 + fr) * 128 + swz);
#pragma unroll
    for (int n = 0; n < 4; ++n)
      bfv[n] = *(const bf16x8*)(bb + (wn * 64 + n * 16 + fr) * 128 + swz);
    if (do_stage) stage_half(ts, bs, h);
    __builtin_amdgcn_s_barrier();
    LGKM0();
    SCHED0();
    __builtin_amdgcn_s_setprio(1);
#pragma unroll
    for (int m = 0; m < 4; ++m)
#pragma unroll
      for (int n = 0; n < 4; ++n)
        acc[m][n] = __builtin_amdgcn_mfma_f32_16x16x32_bf16(af[m], bfv[n], acc[m][n], 0, 0, 0);
    __builtin_amdgcn_s_setprio(0);
  };

  const int NT = D_MODEL / 64;  // 64
  stage_half(0, 0, 0); stage_half(0, 0, 1);
  stage_half(1, 1, 0); stage_half(1, 1, 1);
  VMCNT(6);                       // my tile-0 loads landed (tile-1's 6 still in flight)
  __builtin_amdgcn_s_barrier();   // everyone's tile-0 landed
  SCHED0();
  int cur = 0, nxt = 2;
  for (int t = 0; t < NT - 2; ++t) {
    phase(cur, 0, true, t + 2, nxt, 0);
    __builtin_amdgcn_s_barrier();
    phase(cur, 1, true, t + 2, nxt, 1);
    VMCNT(6);                     // oldest 6 = tile t+1 landed; tile t+2's 6 stay in flight
    __builtin_amdgcn_s_barrier();
    SCHED0();
    cur = (cur == 2) ? 0 : cur + 1;
    nxt = (nxt == 2) ? 0 : nxt + 1;
  }
  phase(cur, 0, false, 0, 0, 0);
  __builtin_amdgcn_s_barrier();
  phase(cur, 1, false, 0, 0, 0);
  VMCNT(0);                       // last tile fully landed
  __builtin_amdgcn_s_barrier();
  SCHED0();
  cur = (cur == 2) ? 0 : cur + 1;
  phase(cur, 0, false, 0, 0, 0);
  __builtin_amdgcn_s_barrier();
  phase(cur, 1, false, 0, 0, 0);

#pragma unroll
  for (int m = 0; m < 4; m++) {
#pragma unroll
    for (int n = 0; n < 4; n++) {
      const int gn = bn0 + wn * 64 + n * 16 + fr;
#pragma unroll
      for (int r = 0; r < 4; r++) {
        const int gm = bm0 + wm * 64 + m * 16 + fq * 4 + r;
        const float vv = acc[m][n][r];
        if constexpr (MODE == 0) {
          const int b = gm >> 10, s = gm & (SEQ - 1), h = gn >> 7, dd = gn & (HD - 1);
          ((bf16_t*)dstv)[((size_t)(b * NH + h) * SEQ + s) * HD + dd] = (bf16_t)vv;
        } else if constexpr (MODE == 1) {
          const int b = gm >> 10, s = gm & (SEQ - 1), h = gn >> 7, dd = gn & (HD - 1);
          ((bf16_t*)dstv)[((size_t)(b * NH + h) * HD + dd) * SEQ + s] = (bf16_t)vv;
        } else {
          if (isbf) ((bf16_t*)dstv)[(size_t)gm * D_MODEL + gn] = (bf16_t)vv;
          else      ((float*)dstv)[(size_t)gm * D_MODEL + gn] = vv;
        }
      }
    }
  }
}

// In-place RoPE on q_ws and k_ws, layout (B,H,S,hd).
__global__ __launch_bounds__(256) void rope_kernel(
    bf16_t* __restrict__ q, bf16_t* __restrict__ k,
    const bf16_t* __restrict__ fcos, const bf16_t* __restrict__ fsin) {
  const int PT = MTOT * (D_MODEL / 2);
  const int p = blockIdx.x * blockDim.x + threadIdx.x;
  bf16_t* buf = (p < PT) ? q : k;
  const int pp = p & (PT - 1);
  const int s = (pp >> 6) & (SEQ - 1);
  const int i = pp & 63;
  const float c = (float)fcos[s * 64 + i];
  const float si = (float)fsin[s * 64 + i];
  const float x0 = (float)buf[2 * (size_t)pp];
  const float x1 = (float)buf[2 * (size_t)pp + 1];
  buf[2 * (size_t)pp] = (bf16_t)(x0 * c - x1 * si);
  buf[2 * (size_t)pp + 1] = (bf16_t)(x0 * si + x1 * c);
}

// Flash attention, causal (round-3 version, unchanged).
__global__ __launch_bounds__(256, 3) void attn_fwd(
    const bf16_t* __restrict__ Q, const bf16_t* __restrict__ K,
    const bf16_t* __restrict__ V, bf16_t* __restrict__ Out) {
  constexpr float SC = 0.088388347648318447f;
  constexpr float MNEG = -10000.0f;
  __shared__ __align__(16) bf16_t Kt[64][136];
  __shared__ __align__(16) bf16_t Vt[128][72];
  __shared__ __align__(16) bf16_t Pb[4][16][72];
  const int tid = threadIdx.x, lane = tid & 63, wid = tid >> 6;
  const int fr = lane & 15, fq = lane >> 4;
  const int qt = (int)gridDim.x - 1 - blockIdx.x;
  const int bh = blockIdx.y;
  const int q0 = qt * 64 + wid * 16;

  const bf16_t* Kbase = K + (size_t)bh * SEQ * HD;
  const bf16_t* Vbase = V + (size_t)bh * HD * SEQ;

  bf16x8 qa[4];
  {
    const bf16_t* qp = Q + ((size_t)bh * SEQ + q0 + fr) * HD + fq * 8;
#pragma unroll
    for (int ks = 0; ks < 4; ++ks) qa[ks] = *(const bf16x8*)(qp + ks * 32);
  }
  f32x4 Oacc[8];
#pragma unroll
  for (int i = 0; i < 8; i++) Oacc[i] = f32x4{0.f, 0.f, 0.f, 0.f};
  float mrow[4] = {MNEG, MNEG, MNEG, MNEG};
  float lrow[4] = {0.f, 0.f, 0.f, 0.f};

  bf16x8 kreg[4], vreg[4];
  auto issue = [&](int kv0) {
#pragma unroll
    for (int j = 0; j < 4; ++j) {
      const int idx = j * 256 + tid;
      kreg[j] = *(const bf16x8*)(Kbase + (size_t)(kv0 + (idx >> 4)) * HD + (idx & 15) * 8);
      vreg[j] = *(const bf16x8*)(Vbase + (size_t)(idx >> 3) * SEQ + kv0 + (idx & 7) * 8);
    }
  };
  auto commit = [&]() {
#pragma unroll
    for (int j = 0; j < 4; ++j) {
      const int idx = j * 256 + tid;
      *(bf16x8*)&Kt[idx >> 4][(idx & 15) * 8] = kreg[j];
      *(bf16x8*)&Vt[idx >> 3][(idx & 7) * 8] = vreg[j];
    }
  };

  const int nt = qt + 1;
  issue(0);
  commit();
  __syncthreads();

  for (int t = 0; t < nt; ++t) {
    const bool last = (t == nt - 1);
    if (!last) issue((t + 1) * 64);

    f32x4 sacc[4];
#pragma unroll
    for (int nb = 0; nb < 4; ++nb) sacc[nb] = f32x4{0.f, 0.f, 0.f, 0.f};
    __builtin_amdgcn_s_setprio(1);
#pragma unroll
    for (int nb = 0; nb < 4; ++nb) {
      const int kvc = nb * 16 + fr;
#pragma unroll
      for (int ks = 0; ks < 4; ++ks) {
        bf16x8 kb = *(const bf16x8*)&Kt[kvc][(ks * 4 + fq) * 8];
        sacc[nb] = __builtin_amdgcn_mfma_f32_16x16x32_bf16(qa[ks], kb, sacc[nb], 0, 0, 0);
      }
    }
    __builtin_amdgcn_s_setprio(0);

    float xv[4][4], al[4];
#pragma unroll
    for (int r = 0; r < 4; ++r) {
      const int qrow = q0 + fq * 4 + r;
#pragma unroll
      for (int nb = 0; nb < 4; ++nb) {
        const float xx = sacc[nb][r] * SC;
        xv[nb][r] = (!last || (t * 64 + nb * 16 + fr) <= qrow) ? xx : MNEG;
      }
      float pm = fmaxf(fmaxf(xv[0][r], xv[1][r]), fmaxf(xv[2][r], xv[3][r]));
      pm = fmaxf(pm, __shfl_xor(pm, 1));
      pm = fmaxf(pm, __shfl_xor(pm, 2));
      pm = fmaxf(pm, __shfl_xor(pm, 4));
      pm = fmaxf(pm, __shfl_xor(pm, 8));
      const float mn = fmaxf(mrow[r], pm);
      al[r] = __expf(mrow[r] - mn);
      mrow[r] = mn;
      float ps = 0.f;
#pragma unroll
      for (int nb = 0; nb < 4; ++nb) {
        const float pv = __expf(xv[nb][r] - mn);
        xv[nb][r] = pv;
        ps += pv;
      }
      lrow[r] = lrow[r] * al[r] + ps;
    }
#pragma unroll
    for (int db = 0; db < 8; ++db)
#pragma unroll
      for (int r = 0; r < 4; ++r) Oacc[db][r] *= al[r];

#pragma unroll
    for (int nb = 0; nb < 4; ++nb)
#pragma unroll
      for (int r = 0; r < 4; ++r)
        Pb[wid][fq * 4 + r][nb * 16 + fr] = (bf16_t)xv[nb][r];
    bf16x8 pa0 = *(const bf16x8*)&Pb[wid][fr][fq * 8];
    bf16x8 pa1 = *(const bf16x8*)&Pb[wid][fr][32 + fq * 8];

    __builtin_amdgcn_s_setprio(1);
#pragma unroll
    for (int db = 0; db < 8; ++db) {
      const int d = db * 16 + fr;
      bf16x8 vb0 = *(const bf16x8*)&Vt[d][fq * 8];
      bf16x8 vb1 = *(const bf16x8*)&Vt[d][32 + fq * 8];
      Oacc[db] = __builtin_amdgcn_mfma_f32_16x16x32_bf16(pa0, vb0, Oacc[db], 0, 0, 0);
      Oacc[db] = __builtin_amdgcn_mfma_f32_16x16x32_bf16(pa1, vb1, Oacc[db], 0, 0, 0);
    }
    __builtin_amdgcn_s_setprio(0);

    if (!last) {
      __syncthreads();
      commit();
      __syncthreads();
    }
  }

  float linv[4];
#pragma unroll
  for (int r = 0; r < 4; ++r) {
    float ps = lrow[r];
    ps += __shfl_xor(ps, 1);
    ps += __shfl_xor(ps, 2);
    ps += __shfl_xor(ps, 4);
    ps += __shfl_xor(ps, 8);
    linv[r] = 1.0f / fmaxf(ps, 1e-20f);
  }

  const int b = bh >> 5, h = bh & 31;
#pragma unroll
  for (int db = 0; db < 8; ++db) {
    const int d = db * 16 + fr;
#pragma unroll
    for (int r = 0; r < 4; ++r) {
      const int q = q0 + fq * 4 + r;
      Out[((size_t)(b * SEQ + q)) * D_MODEL + h * HD + d] = (bf16_t)(Oacc[db][r] * linv[r]);
    }
  }
}

extern "C" void kernel_launch(void* const* d_in, const int* in_sizes, int n_in,
                              void* d_out, int out_size, void* d_ws, size_t ws_size,
                              hipStream_t stream) {
  (void)in_sizes; (void)n_in; (void)out_size;
  const void* x_raw    = d_in[0];
  const void* fcos_raw = d_in[2];
  const void* fsin_raw = d_in[3];
  const void* wq_raw   = d_in[7];
  const void* wk_raw   = d_in[8];
  const void* wv_raw   = d_in[9];
  const void* wo_raw   = d_in[10];

  const size_t NX = (size_t)MTOT * D_MODEL;
  const size_t NW = (size_t)D_MODEL * D_MODEL;
  const size_t NF = SEQ * (HD / 2);

  char* base = (char*)d_ws;
  uint32_t* flag = (uint32_t*)base;
  bf16_t* fc = (bf16_t*)(base + 4096);
  bf16_t* fs = (bf16_t*)(base + 4096 + 131072);
  bf16_t* elems = (bf16_t*)(base + (1 << 20));
  bf16_t* xc = elems;
  bf16_t* w0 = xc + NX;
  bf16_t* w1 = w0 + NW;
  bf16_t* q_ws = w1 + NW;
  bf16_t* k_ws = q_ws + NX;
  bf16_t* v_ws = k_ws + NX;
  bf16_t* a_ws = v_ws + NX;
  const size_t NEED = (1 << 20) + 2 * (5 * NX + 2 * NW);
  if (ws_size < NEED) return;

  dtype_probe<<<1, 64, 0, stream>>>((const uint32_t*)x_raw, flag);

  const int cb_x = (int)(NX / (256 * 8));
  const int cb_w = (int)(NW / (256 * 8));
  const int cb_f = (int)(NF / (256 * 8));
  conv_bf16<<<cb_x, 256, 0, stream>>>(x_raw, xc, (int)NX, flag);
  conv_bf16<<<cb_f, 256, 0, stream>>>(fcos_raw, fc, (int)NF, flag);
  conv_bf16<<<cb_f, 256, 0, stream>>>(fsin_raw, fs, (int)NF, flag);

  dim3 gg(MTOT / 128, D_MODEL / 256);
  conv_bf16<<<cb_w, 256, 0, stream>>>(wq_raw, w0, (int)NW, flag);
  gemm_bt<0><<<gg, 512, 0, stream>>>(xc, w0, q_ws, flag);
  conv_bf16<<<cb_w, 256, 0, stream>>>(wk_raw, w1, (int)NW, flag);
  gemm_bt<0><<<gg, 512, 0, stream>>>(xc, w1, k_ws, flag);
  conv_bf16<<<cb_w, 256, 0, stream>>>(wv_raw, w0, (int)NW, flag);
  gemm_bt<1><<<gg, 512, 0, stream>>>(xc, w0, v_ws, flag);

  rope_kernel<<<(2 * MTOT * (D_MODEL / 2)) / 256, 256, 0, stream>>>(q_ws, k_ws, fc, fs);
  attn_fwd<<<dim3(SEQ / 64, 2 * NH), 256, 0, stream>>>(q_ws, k_ws, v_ws, a_ws);

  conv_bf16<<<cb_w, 256, 0, stream>>>(wo_raw, w1, (int)NW, flag);
  gemm_bt<2><<<gg, 512, 0, stream>>>(a_ws, w1, d_out, flag);
}

// Round 7
// 415.649 us; speedup vs baseline: 1.3997x; 1.0559x over previous
//
#include <hip/hip_runtime.h>
#include <hip/hip_bf16.h>
#include <stdint.h>
#include <stddef.h>

typedef __bf16 bf16_t;
typedef __attribute__((ext_vector_type(8))) __bf16 bf16x8;
typedef __attribute__((ext_vector_type(4))) float f32x4;
typedef __attribute__((ext_vector_type(16))) float f32x16;
typedef __attribute__((ext_vector_type(4))) uint32_t u32x4;

#define D_MODEL 4096
#define SEQ 1024
#define NH 32
#define HD 128
#define MTOT 2048 /* B*S */

#define VMCNT(n) asm volatile("s_waitcnt vmcnt(" #n ")" ::: "memory")
#define LGKM0() asm volatile("s_waitcnt lgkmcnt(0)" ::: "memory")
#define SCHED0() __builtin_amdgcn_sched_barrier(0)

__device__ __forceinline__ void gload_lds16(const void* g, void* l) {
  __builtin_amdgcn_global_load_lds((const __attribute__((address_space(1))) uint32_t*)g,
                                   (__attribute__((address_space(3))) uint32_t*)l, 16, 0, 0);
}

__device__ __forceinline__ uint32_t cvtpk(float lo, float hi) {
  uint32_t r;
  asm("v_cvt_pk_bf16_f32 %0, %1, %2" : "=v"(r) : "v"(lo), "v"(hi));
  return r;
}
__device__ __forceinline__ void plswap(uint32_t& a, uint32_t& b) {
  asm volatile("v_permlane32_swap_b32 %0, %1" : "+v"(a), "+v"(b));
}

// Decide input dtype from x's bit patterns (proven round 2).
__global__ void dtype_probe(const uint32_t* __restrict__ x, uint32_t* __restrict__ flag) {
  const int lane = threadIdx.x & 63;
  const uint32_t w = x[lane];
  const uint32_t e = (w >> 7) & 0xFF;
  const bool inband = (e >= 100 && e <= 140);
  const unsigned long long m = __ballot(inband);
  if (lane == 0) *flag = (__popcll(m) >= 32) ? 1u : 0u;  // 1 = bf16, 0 = fp32
}

__global__ __launch_bounds__(256) void conv_bf16(const void* __restrict__ src,
                                                 bf16_t* __restrict__ dst, int n,
                                                 const uint32_t* __restrict__ flag) {
  const int i = (blockIdx.x * 256 + threadIdx.x) * 8;
  if (i >= n) return;
  if (*flag) {
    *(bf16x8*)(dst + i) = *(const bf16x8*)((const bf16_t*)src + i);
  } else {
    const float4 a = *(const float4*)((const float*)src + i);
    const float4 b = *(const float4*)((const float*)src + i + 4);
    bf16x8 v;
    v[0] = (bf16_t)a.x; v[1] = (bf16_t)a.y; v[2] = (bf16_t)a.z; v[3] = (bf16_t)a.w;
    v[4] = (bf16_t)b.x; v[5] = (bf16_t)b.y; v[6] = (bf16_t)b.z; v[7] = (bf16_t)b.w;
    *(bf16x8*)(dst + i) = v;
  }
}

// C[M,N] = A[M,K] * B[N,K]^T — 2-phase deep-pipelined NT GEMM (round-5, proven).
template <int MODE>
__global__ __launch_bounds__(512, 2) void gemm_bt(
    const bf16_t* __restrict__ A, const bf16_t* __restrict__ B,
    void* __restrict__ dstv, const uint32_t* __restrict__ flagp) {
  __shared__ __align__(16) char smem[3 * 49152];
  const int tid = threadIdx.x;
  const int lane = tid & 63, wid = tid >> 6;
  const int fr = lane & 15, fq = lane >> 4;
  const int wm = wid >> 2, wn = wid & 3;
  const int bm0 = blockIdx.x * 128, bn0 = blockIdx.y * 256;
  const bool isbf = (MODE == 2) ? (*flagp != 0) : true;

  auto stage_half = [&](int t, int bi, int h) {
    const int k0 = t * 64;
    char* ab = smem + bi * 49152;
    char* bb = ab + 16384;
    {
      const int o = h * 8192 + tid * 16;
      const int row = o >> 7, ch = (o >> 4) & 7;
      gload_lds16(A + (size_t)(bm0 + row) * D_MODEL + k0 + ((ch ^ (row & 7)) * 8), ab + o);
    }
#pragma unroll
    for (int j = 0; j < 2; ++j) {
      const int o = (h * 2 + j) * 8192 + tid * 16;
      const int row = o >> 7, ch = (o >> 4) & 7;
      gload_lds16(B + (size_t)(bn0 + row) * D_MODEL + k0 + ((ch ^ (row & 7)) * 8), bb + o);
    }
  };

  f32x4 acc[4][4];
#pragma unroll
  for (int m = 0; m < 4; m++)
#pragma unroll
    for (int n = 0; n < 4; n++) acc[m][n] = f32x4{0.f, 0.f, 0.f, 0.f};

  auto phase = [&](int bi, int kk, bool do_stage, int ts, int bs, int h) {
    const char* ab = smem + bi * 49152;
    const char* bb = ab + 16384;
    const int swz = ((kk * 4 + fq) ^ (fr & 7)) << 4;
    bf16x8 af[4], bfv[4];
#pragma unroll
    for (int m = 0; m < 4; ++m)
      af[m] = *(const bf16x8*)(ab + (wm * 64 + m * 16 + fr) * 128 + swz);
#pragma unroll
    for (int n = 0; n < 4; ++n)
      bfv[n] = *(const bf16x8*)(bb + (wn * 64 + n * 16 + fr) * 128 + swz);
    if (do_stage) stage_half(ts, bs, h);
    __builtin_amdgcn_s_barrier();
    LGKM0();
    SCHED0();
    __builtin_amdgcn_s_setprio(1);
#pragma unroll
    for (int m = 0; m < 4; ++m)
#pragma unroll
      for (int n = 0; n < 4; ++n)
        acc[m][n] = __builtin_amdgcn_mfma_f32_16x16x32_bf16(af[m], bfv[n], acc[m][n], 0, 0, 0);
    __builtin_amdgcn_s_setprio(0);
  };

  const int NT = D_MODEL / 64;
  stage_half(0, 0, 0); stage_half(0, 0, 1);
  stage_half(1, 1, 0); stage_half(1, 1, 1);
  VMCNT(6);
  __builtin_amdgcn_s_barrier();
  SCHED0();
  int cur = 0, nxt = 2;
  for (int t = 0; t < NT - 2; ++t) {
    phase(cur, 0, true, t + 2, nxt, 0);
    __builtin_amdgcn_s_barrier();
    phase(cur, 1, true, t + 2, nxt, 1);
    VMCNT(6);
    __builtin_amdgcn_s_barrier();
    SCHED0();
    cur = (cur == 2) ? 0 : cur + 1;
    nxt = (nxt == 2) ? 0 : nxt + 1;
  }
  phase(cur, 0, false, 0, 0, 0);
  __builtin_amdgcn_s_barrier();
  phase(cur, 1, false, 0, 0, 0);
  VMCNT(0);
  __builtin_amdgcn_s_barrier();
  SCHED0();
  cur = (cur == 2) ? 0 : cur + 1;
  phase(cur, 0, false, 0, 0, 0);
  __builtin_amdgcn_s_barrier();
  phase(cur, 1, false, 0, 0, 0);

#pragma unroll
  for (int m = 0; m < 4; m++) {
#pragma unroll
    for (int n = 0; n < 4; n++) {
      const int gn = bn0 + wn * 64 + n * 16 + fr;
#pragma unroll
      for (int r = 0; r < 4; r++) {
        const int gm = bm0 + wm * 64 + m * 16 + fq * 4 + r;
        const float vv = acc[m][n][r];
        if constexpr (MODE == 0) {
          const int b = gm >> 10, s = gm & (SEQ - 1), h = gn >> 7, dd = gn & (HD - 1);
          ((bf16_t*)dstv)[((size_t)(b * NH + h) * SEQ + s) * HD + dd] = (bf16_t)vv;
        } else if constexpr (MODE == 1) {
          const int b = gm >> 10, s = gm & (SEQ - 1), h = gn >> 7, dd = gn & (HD - 1);
          ((bf16_t*)dstv)[((size_t)(b * NH + h) * HD + dd) * SEQ + s] = (bf16_t)vv;
        } else {
          if (isbf) ((bf16_t*)dstv)[(size_t)gm * D_MODEL + gn] = (bf16_t)vv;
          else      ((float*)dstv)[(size_t)gm * D_MODEL + gn] = vv;
        }
      }
    }
  }
}

// In-place RoPE on q_ws and k_ws, layout (B,H,S,hd).
__global__ __launch_bounds__(256) void rope_kernel(
    bf16_t* __restrict__ q, bf16_t* __restrict__ k,
    const bf16_t* __restrict__ fcos, const bf16_t* __restrict__ fsin) {
  const int PT = MTOT * (D_MODEL / 2);
  const int p = blockIdx.x * blockDim.x + threadIdx.x;
  bf16_t* buf = (p < PT) ? q : k;
  const int pp = p & (PT - 1);
  const int s = (pp >> 6) & (SEQ - 1);
  const int i = pp & 63;
  const float c = (float)fcos[s * 64 + i];
  const float si = (float)fsin[s * 64 + i];
  const float x0 = (float)buf[2 * (size_t)pp];
  const float x1 = (float)buf[2 * (size_t)pp + 1];
  buf[2 * (size_t)pp] = (bf16_t)(x0 * c - x1 * si);
  buf[2 * (size_t)pp + 1] = (bf16_t)(x0 * si + x1 * c);
}

// Flash attention v3: 8 waves x 32 q-rows (block = 256 q), KVB=64, 32x32x16 MFMA,
// swapped QK^T (lane-local softmax), transposed PV (per-lane rescale), T12 P-redistribution.
// Grid (4, B*H). Q,K layout (B,H,S,hd); V layout (B,H,hd,S) = V^T rows.
__global__ __launch_bounds__(512, 2) void attn_fwd(
    const bf16_t* __restrict__ Q, const bf16_t* __restrict__ K,
    const bf16_t* __restrict__ V, bf16_t* __restrict__ Out) {
  constexpr float SC = 0.088388347648318447f;  // 1/sqrt(128)
  constexpr float MNEG = -10000.0f;
  __shared__ __align__(16) char smem[65536];  // [K0 16K][K1 16K][V0 16K][V1 16K]; epilogue: O 256x256B
  const int tid = threadIdx.x, lane = tid & 63, wid = tid >> 6;
  const int l31 = lane & 31, hi = lane >> 5, l7 = lane & 7;
  const int qt = 3 - (int)blockIdx.x;  // heavy-first
  const int bh = blockIdx.y;
  const int qb0 = qt * 256;
  const int q0w = qb0 + wid * 32;
  const int nt = qt * 4 + 4;

  const bf16_t* Kbase = K + (size_t)bh * SEQ * HD;
  const bf16_t* Vbase = V + (size_t)bh * HD * SEQ;

  // Q -> regs: B-frag for swapped QK (lane: q = l31, k = ks*16 + hi*8 + j)
  bf16x8 qa[8];
  {
    const bf16_t* qp = Q + ((size_t)bh * SEQ + q0w + l31) * HD + hi * 8;
#pragma unroll
    for (int ks = 0; ks < 8; ++ks) qa[ks] = *(const bf16x8*)(qp + ks * 16);
  }

  auto stage = [&](int t, int bi) {
    const int kv0 = t * 64;
#pragma unroll
    for (int pass = 0; pass < 2; ++pass) {
      const int o = pass * 8192 + tid * 16;
      {  // K tile 64 x 128 bf16 (256B rows), chunk ^= row&7, linear dest
        const int row = o >> 8, ch = (o & 255) >> 4;
        gload_lds16(Kbase + (size_t)(kv0 + row) * HD + ((ch ^ (row & 7)) * 8),
                    smem + bi * 16384 + o);
      }
      {  // V^T tile 128 x 64 bf16 (128B rows)
        const int row = o >> 7, ch = (o & 127) >> 4;
        gload_lds16(Vbase + (size_t)row * SEQ + kv0 + ((ch ^ (row & 7)) * 8),
                    smem + 32768 + bi * 16384 + o);
      }
    }
  };

  f32x16 Oacc[4];  // O^T fragments: col=q=l31, row d = crow(reg,hi)+db*32
#pragma unroll
  for (int i = 0; i < 4; ++i)
#pragma unroll
    for (int j = 0; j < 16; ++j) Oacc[i][j] = 0.f;
  float mrow = MNEG, lrow = 0.f;

  stage(0, 0);
  stage(1, 1);
  VMCNT(4);
  __builtin_amdgcn_s_barrier();

  for (int t = 0; t < nt; ++t) {
    const int kv0 = t * 64;
    if (kv0 < q0w + 32) {  // wave participates (wave-uniform)
      const char* kb_ = smem + (t & 1) * 16384;
      const char* vb_ = smem + 32768 + (t & 1) * 16384;

      // ---- S^T = K Q^T : sacc[kb] C-layout col=q=l31, row kv=crow(reg,hi)+kb*32 ----
      f32x16 sacc[2];
#pragma unroll
      for (int kb = 0; kb < 2; ++kb)
#pragma unroll
        for (int j = 0; j < 16; ++j) sacc[kb][j] = 0.f;
      __builtin_amdgcn_s_setprio(1);
#pragma unroll
      for (int kb = 0; kb < 2; ++kb)
#pragma unroll
        for (int ks = 0; ks < 8; ++ks) {
          bf16x8 kf = *(const bf16x8*)(kb_ + (kb * 32 + l31) * 256 +
                                       (((ks * 2 + hi) ^ l7) << 4));
          sacc[kb] = __builtin_amdgcn_mfma_f32_32x32x16_bf16(kf, qa[ks], sacc[kb], 0, 0, 0);
        }
      __builtin_amdgcn_s_setprio(0);

      // ---- online softmax, fully lane-local (q = l31) ----
      const bool diag = (kv0 + 63 > q0w);
      float pm = MNEG;
#pragma unroll
      for (int kb = 0; kb < 2; ++kb)
#pragma unroll
        for (int r = 0; r < 16; ++r) {
          float x = sacc[kb][r] * SC;
          if (diag) {
            const int kvpos = kv0 + kb * 32 + (r & 3) + 8 * (r >> 2) + 4 * hi;
            if (kvpos > q0w + l31) x = MNEG;
          }
          sacc[kb][r] = x;
          pm = fmaxf(pm, x);
        }
      pm = fmaxf(pm, __shfl_xor(pm, 32));
      const float mn = fmaxf(mrow, pm);
      const float al = __expf(mrow - mn);
      mrow = mn;
      float ps = 0.f;
#pragma unroll
      for (int kb = 0; kb < 2; ++kb)
#pragma unroll
        for (int r = 0; r < 16; ++r) {
          const float e = __expf(sacc[kb][r] - mn);
          sacc[kb][r] = e;
          ps += e;
        }
      lrow = lrow * al + ps;
#pragma unroll
      for (int db = 0; db < 4; ++db)
#pragma unroll
        for (int j = 0; j < 16; ++j) Oacc[db][j] *= al;

      // ---- P -> B-frag layout via cvt_pk + permlane32_swap (T12) ----
      uint32_t pw[16];
#pragma unroll
      for (int kb = 0; kb < 2; ++kb) {
        const int o8 = kb * 8;
        pw[o8 + 0] = cvtpk(sacc[kb][0], sacc[kb][1]);
        pw[o8 + 1] = cvtpk(sacc[kb][2], sacc[kb][3]);
        pw[o8 + 2] = cvtpk(sacc[kb][4], sacc[kb][5]);
        pw[o8 + 3] = cvtpk(sacc[kb][6], sacc[kb][7]);
        plswap(pw[o8 + 0], pw[o8 + 2]);
        plswap(pw[o8 + 1], pw[o8 + 3]);
        pw[o8 + 4] = cvtpk(sacc[kb][8], sacc[kb][9]);
        pw[o8 + 5] = cvtpk(sacc[kb][10], sacc[kb][11]);
        pw[o8 + 6] = cvtpk(sacc[kb][12], sacc[kb][13]);
        pw[o8 + 7] = cvtpk(sacc[kb][14], sacc[kb][15]);
        plswap(pw[o8 + 4], pw[o8 + 6]);
        plswap(pw[o8 + 5], pw[o8 + 7]);
      }

      // ---- O^T += V^T P : A=V^T (rows d), B=P (rows q) ----
      __builtin_amdgcn_s_setprio(1);
#pragma unroll
      for (int db = 0; db < 4; ++db)
#pragma unroll
        for (int ks2 = 0; ks2 < 4; ++ks2) {
          bf16x8 vf = *(const bf16x8*)(vb_ + (db * 32 + l31) * 128 +
                                       (((ks2 * 2 + hi) ^ l7) << 4));
          union { u32x4 u; bf16x8 v; } pc;
          pc.u = u32x4{pw[ks2 * 4], pw[ks2 * 4 + 1], pw[ks2 * 4 + 2], pw[ks2 * 4 + 3]};
          Oacc[db] = __builtin_amdgcn_mfma_f32_32x32x16_bf16(vf, pc.v, Oacc[db], 0, 0, 0);
        }
      __builtin_amdgcn_s_setprio(0);
    }

    __builtin_amdgcn_s_barrier();  // all waves done reading buf t&1
    if (t + 2 < nt) {
      stage(t + 2, t & 1);
      VMCNT(4);  // t+1's 4 loads landed; t+2's stay in flight
    } else if (t + 1 < nt) {
      VMCNT(0);
    }
    __builtin_amdgcn_s_barrier();
  }

  lrow += __shfl_xor(lrow, 32);
  const float linv = 1.0f / fmaxf(lrow, 1e-20f);

  // ---- O^T -> LDS [256 q][128 d] bf16 (chunk ^= q&7) -> coalesced global ----
  {
    char* ob = smem + wid * 8192;
#pragma unroll
    for (int db = 0; db < 4; ++db)
#pragma unroll
      for (int rp = 0; rp < 8; ++rp) {
        const int r = rp * 2;
        const int d = db * 32 + (r & 3) + 8 * (r >> 2) + 4 * hi;
        const uint32_t w = cvtpk(Oacc[db][r] * linv, Oacc[db][r + 1] * linv);
        *(uint32_t*)(ob + l31 * 256 + ((d * 2) ^ ((l31 & 7) << 4))) = w;
      }
  }
  __builtin_amdgcn_s_barrier();
  const int b = bh >> 5, h = bh & 31;
#pragma unroll
  for (int pass = 0; pass < 8; ++pass) {
    const int o = pass * 8192 + tid * 16;
    const int row = o >> 8, ch = (o & 255) >> 4;
    const u32x4 val = *(const u32x4*)(smem + row * 256 + ((ch ^ (row & 7)) << 4));
    *(u32x4*)(Out + ((size_t)(b * SEQ + qb0 + row)) * D_MODEL + h * HD + ch * 8) = val;
  }
}

extern "C" void kernel_launch(void* const* d_in, const int* in_sizes, int n_in,
                              void* d_out, int out_size, void* d_ws, size_t ws_size,
                              hipStream_t stream) {
  (void)in_sizes; (void)n_in; (void)out_size;
  const void* x_raw    = d_in[0];
  const void* fcos_raw = d_in[2];
  const void* fsin_raw = d_in[3];
  const void* wq_raw   = d_in[7];
  const void* wk_raw   = d_in[8];
  const void* wv_raw   = d_in[9];
  const void* wo_raw   = d_in[10];

  const size_t NX = (size_t)MTOT * D_MODEL;
  const size_t NW = (size_t)D_MODEL * D_MODEL;
  const size_t NF = SEQ * (HD / 2);

  char* base = (char*)d_ws;
  uint32_t* flag = (uint32_t*)base;
  bf16_t* fc = (bf16_t*)(base + 4096);
  bf16_t* fs = (bf16_t*)(base + 4096 + 131072);
  bf16_t* elems = (bf16_t*)(base + (1 << 20));
  bf16_t* xc = elems;
  bf16_t* w0 = xc + NX;
  bf16_t* w1 = w0 + NW;
  bf16_t* q_ws = w1 + NW;
  bf16_t* k_ws = q_ws + NX;
  bf16_t* v_ws = k_ws + NX;
  bf16_t* a_ws = v_ws + NX;
  const size_t NEED = (1 << 20) + 2 * (5 * NX + 2 * NW);
  if (ws_size < NEED) return;

  dtype_probe<<<1, 64, 0, stream>>>((const uint32_t*)x_raw, flag);

  const int cb_x = (int)(NX / (256 * 8));
  const int cb_w = (int)(NW / (256 * 8));
  const int cb_f = (int)(NF / (256 * 8));
  conv_bf16<<<cb_x, 256, 0, stream>>>(x_raw, xc, (int)NX, flag);
  conv_bf16<<<cb_f, 256, 0, stream>>>(fcos_raw, fc, (int)NF, flag);
  conv_bf16<<<cb_f, 256, 0, stream>>>(fsin_raw, fs, (int)NF, flag);

  dim3 gg(MTOT / 128, D_MODEL / 256);
  conv_bf16<<<cb_w, 256, 0, stream>>>(wq_raw, w0, (int)NW, flag);
  gemm_bt<0><<<gg, 512, 0, stream>>>(xc, w0, q_ws, flag);
  conv_bf16<<<cb_w, 256, 0, stream>>>(wk_raw, w1, (int)NW, flag);
  gemm_bt<0><<<gg, 512, 0, stream>>>(xc, w1, k_ws, flag);
  conv_bf16<<<cb_w, 256, 0, stream>>>(wv_raw, w0, (int)NW, flag);
  gemm_bt<1><<<gg, 512, 0, stream>>>(xc, w0, v_ws, flag);

  rope_kernel<<<(2 * MTOT * (D_MODEL / 2)) / 256, 256, 0, stream>>>(q_ws, k_ws, fc, fs);
  attn_fwd<<<dim3(4, 2 * NH), 512, 0, stream>>>(q_ws, k_ws, v_ws, a_ws);

  conv_bf16<<<cb_w, 256, 0, stream>>>(wo_raw, w1, (int)NW, flag);
  gemm_bt<2><<<gg, 512, 0, stream>>>(a_ws, w1, d_out, flag);
}